// Round 7
// baseline (50.155 us; speedup 1.0000x reference)
//
#include <hip/hip_runtime.h>
#include <math.h>

typedef float f32x2 __attribute__((ext_vector_type(2)));
typedef f32x2 f32x2_u __attribute__((aligned(4)));
typedef float float_u __attribute__((aligned(4)));

#define TWO_PI 6.283185307179586f
#define SMOOTH 0.1f
#define SPW 8                  // stations per WAVE
#define WAVES 4
#define BLOCK 256
#define SPB (SPW * WAVES)      // 32 stations per block
#define NPAIR 3                // column pairs per thread

__device__ __forceinline__ f32x2 sp2(float x) { f32x2 r; r.x = x; r.y = x; return r; }

// v6 = v5 with ONE change: nontemporal stores (nt flag -> no L2 write-allocate,
// streaming write-combine). Tests the write-allocate-fetch theory: harness
// poisons d_out leaving L2 full of dirty lines; if our misaligned 512-B
// segments don't full-line-combine, every line costs an HBM fetch (~146 MB
// extra traffic = the observed ~18 us excess over the write floor).
__device__ __forceinline__ void store8_nt(float* p, f32x2 v) {
    __builtin_nontemporal_store(v, (f32x2_u*)p);
}
__device__ __forceinline__ void store4_nt(float* p, float v) {
    __builtin_nontemporal_store(v, (float_u*)p);
}

__device__ __forceinline__ float rlane(float v, int l) {
    return __uint_as_float((unsigned)__builtin_amdgcn_readlane((int)__float_as_uint(v), l));
}

__global__ __launch_bounds__(BLOCK) void fused_v6(
    const float* __restrict__ time_vector,
    const float* __restrict__ constant_offset,
    const float* __restrict__ linear_trend,
    const float* __restrict__ amps,      // [N][4]
    const float* __restrict__ phs,       // [N][4]
    const float* __restrict__ wgt,       // [N][K]
    const float* __restrict__ periods,   // [4]
    const int*   __restrict__ nbidx,     // [N][K]
    float* __restrict__ out,             // [N][T]
    int N, int T, int K)
{
    const int tid   = threadIdx.x;
    const int wave  = tid >> 6;
    const int lane  = tid & 63;
    const int wbase = blockIdx.x * SPB + wave * SPW;

    if (wbase >= N) return;
    int send = N - wbase; if (send > SPW) send = SPW;

    // ---- Phase 1: all lanes compute coefs of station wbase+(lane&7) ----
    int sid = wbase + (lane & (SPW - 1));
    if (sid >= N) sid = N - 1;

    float4 a = reinterpret_cast<const float4*>(amps)[sid];
    float4 p = reinterpret_cast<const float4*>(phs)[sid];

    int   nb[5]; float w[5];
    __builtin_memcpy(nb, nbidx + (size_t)sid * K, 5 * sizeof(int));
    __builtin_memcpy(w,  wgt   + (size_t)sid * K, 5 * sizeof(float));

    float av0 = 0.f, av1 = 0.f, av2 = 0.f, av3 = 0.f;
    float pv0 = 0.f, pv1 = 0.f, pv2 = 0.f, pv3 = 0.f;
    #pragma unroll
    for (int k = 0; k < 5; ++k) {
        float4 na = reinterpret_cast<const float4*>(amps)[nb[k]];
        float4 np = reinterpret_cast<const float4*>(phs)[nb[k]];
        av0 += w[k] * na.x; av1 += w[k] * na.y; av2 += w[k] * na.z; av3 += w[k] * na.w;
        pv0 += w[k] * np.x; pv1 += w[k] * np.y; pv2 += w[k] * np.z; pv3 += w[k] * np.w;
    }
    float sa0 = (1.0f - SMOOTH) * a.x + SMOOTH * av0;
    float sa1 = (1.0f - SMOOTH) * a.y + SMOOTH * av1;
    float sa2 = (1.0f - SMOOTH) * a.z + SMOOTH * av2;
    float sa3 = (1.0f - SMOOTH) * a.w + SMOOTH * av3;
    float sp0 = (1.0f - SMOOTH) * p.x + SMOOTH * pv0;
    float sp1 = (1.0f - SMOOTH) * p.y + SMOOTH * pv1;
    float sp2v = (1.0f - SMOOTH) * p.z + SMOOTH * pv2;
    float sp3 = (1.0f - SMOOTH) * p.w + SMOOTH * pv3;

    float cc = constant_offset[sid];
    float cm = linear_trend[sid];
    float cA0 = sa0 * __cosf(sp0),  cB0 = sa0 * __sinf(sp0);
    float cA1 = sa1 * __cosf(sp1),  cB1 = sa1 * __sinf(sp1);
    float cA2 = sa2 * __cosf(sp2v), cB2 = sa2 * __sinf(sp2v);
    float cA3 = sa3 * __cosf(sp3),  cB3 = sa3 * __sinf(sp3);

    // ---- Basis: 3 adjacent column pairs per thread, in registers ----
    const float w0 = TWO_PI / periods[0];
    const float w1 = TWO_PI / periods[1];
    const float w2 = TWO_PI / periods[2];
    const float w3 = TWO_PI / periods[3];

    f32x2 tv[NPAIR];
    f32x2 bs[NPAIR][4], bc[NPAIR][4];
    bool full[NPAIR], any[NPAIR];
    const int t0 = 2 * lane;

    #pragma unroll
    for (int q = 0; q < NPAIR; ++q) {
        const int t = t0 + 128 * q;
        const bool v0 = (t < T), v1 = (t + 1 < T);
        any[q] = v0; full[q] = v1;
        float ta = v0 ? time_vector[t]     : 0.f;
        float tb = v1 ? time_vector[t + 1] : 0.f;
        f32x2 tvp; tvp.x = ta; tvp.y = tb;
        tv[q] = tvp;
        #pragma unroll
        for (int f = 0; f < 4; ++f) {
            const float wf = (f == 0) ? w0 : (f == 1) ? w1 : (f == 2) ? w2 : w3;
            f32x2 s, c;
            s.x = __sinf(wf * ta); s.y = __sinf(wf * tb);
            c.x = __cosf(wf * ta); c.y = __cosf(wf * tb);
            bs[q][f] = s; bc[q][f] = c;
        }
    }

    // ---- j-loop: station j's coefs via readlane (SGPR broadcast) ----
    float* obase = out + (size_t)wbase * T;

    #pragma unroll
    for (int j = 0; j < SPW; ++j) {
        if (j >= send) break;                 // uniform branch
        float sc  = rlane(cc,  j), sm  = rlane(cm,  j);
        float sA0 = rlane(cA0, j), sB0 = rlane(cB0, j);
        float sA1 = rlane(cA1, j), sB1 = rlane(cB1, j);
        float sA2 = rlane(cA2, j), sB2 = rlane(cB2, j);
        float sA3 = rlane(cA3, j), sB3 = rlane(cB3, j);
        float* orow = obase + (size_t)j * T;

        #pragma unroll
        for (int q = 0; q < NPAIR; ++q) {
            f32x2 sig = sp2(sc) + sp2(sm) * tv[q];
            sig += sp2(sA0) * bs[q][0] + sp2(sB0) * bc[q][0];
            sig += sp2(sA1) * bs[q][1] + sp2(sB1) * bc[q][1];
            sig += sp2(sA2) * bs[q][2] + sp2(sB2) * bc[q][2];
            sig += sp2(sA3) * bs[q][3] + sp2(sB3) * bc[q][3];
            const int t = t0 + 128 * q;
            if (full[q])      store8_nt(orow + t, sig);
            else if (any[q])  store4_nt(orow + t, sig.x);
        }
    }
}

extern "C" void kernel_launch(void* const* d_in, const int* in_sizes, int n_in,
                              void* d_out, int out_size, void* d_ws, size_t ws_size,
                              hipStream_t stream)
{
    const float* time_vector     = (const float*)d_in[0];
    const float* constant_offset = (const float*)d_in[1];
    const float* linear_trend    = (const float*)d_in[2];
    const float* amps            = (const float*)d_in[3];
    const float* phs             = (const float*)d_in[4];
    const float* wgt             = (const float*)d_in[5];
    const float* periods         = (const float*)d_in[6];
    const int*   nbidx           = (const int*)d_in[7];

    int T = in_sizes[0];
    int N = in_sizes[1];
    int K = in_sizes[5] / N;
    float* out = (float*)d_out;

    int grid = (N + SPB - 1) / SPB;
    fused_v6<<<grid, BLOCK, 0, stream>>>(
        time_vector, constant_offset, linear_trend, amps, phs, wgt,
        periods, nbidx, out, N, T, K);
}

// Round 8
// 40.408 us; speedup vs baseline: 1.2412x; 1.2412x over previous
//
#include <hip/hip_runtime.h>
#include <math.h>

typedef float f32x2 __attribute__((ext_vector_type(2)));

#define TWO_PI 6.283185307179586f
#define SMOOTH 0.1f
#define SPW 8                  // stations per WAVE
#define WAVES 4
#define BLOCK 256
#define SPB (SPW * WAVES)      // 32 stations per block
#define NPAIR 3                // column pairs per thread
#define HROWS 4                // rows staged per half-slab

__device__ __forceinline__ f32x2 sp2(float x) { f32x2 r; r.x = x; r.y = x; return r; }
__device__ __forceinline__ float rlane(float v, int l) {
    return __uint_as_float((unsigned)__builtin_amdgcn_readlane((int)__float_as_uint(v), l));
}

// v7 = v5 compute, but stores go through a wave-private LDS slab so the
// global write stream becomes lane-linear, 16B-aligned dwordx4 — the same
// instruction pattern as the 6.8 TB/s fill kernel. Tests (and fixes, if
// true) the odd-row 4B-misaligned-dwordx2 theory for the ~18us excess.
__global__ __launch_bounds__(BLOCK) void fused_v7(
    const float* __restrict__ time_vector,
    const float* __restrict__ constant_offset,
    const float* __restrict__ linear_trend,
    const float* __restrict__ amps,      // [N][4]
    const float* __restrict__ phs,       // [N][4]
    const float* __restrict__ wgt,       // [N][K]
    const float* __restrict__ periods,   // [4]
    const int*   __restrict__ nbidx,     // [N][K]
    float* __restrict__ out,             // [N][T]
    int N, int T, int K)
{
    extern __shared__ float lds[];       // WAVES * HROWS * T floats

    const int tid   = threadIdx.x;
    const int wave  = tid >> 6;
    const int lane  = tid & 63;
    const int wbase = blockIdx.x * SPB + wave * SPW;

    if (wbase >= N) return;
    int send = N - wbase; if (send > SPW) send = SPW;

    // ---- Phase 1: all lanes compute coefs of station wbase+(lane&7) ----
    int sid = wbase + (lane & (SPW - 1));
    if (sid >= N) sid = N - 1;

    float4 a = reinterpret_cast<const float4*>(amps)[sid];
    float4 p = reinterpret_cast<const float4*>(phs)[sid];

    int   nb[5]; float w[5];
    __builtin_memcpy(nb, nbidx + (size_t)sid * K, 5 * sizeof(int));
    __builtin_memcpy(w,  wgt   + (size_t)sid * K, 5 * sizeof(float));

    float av0 = 0.f, av1 = 0.f, av2 = 0.f, av3 = 0.f;
    float pv0 = 0.f, pv1 = 0.f, pv2 = 0.f, pv3 = 0.f;
    #pragma unroll
    for (int k = 0; k < 5; ++k) {
        float4 na = reinterpret_cast<const float4*>(amps)[nb[k]];
        float4 np = reinterpret_cast<const float4*>(phs)[nb[k]];
        av0 += w[k] * na.x; av1 += w[k] * na.y; av2 += w[k] * na.z; av3 += w[k] * na.w;
        pv0 += w[k] * np.x; pv1 += w[k] * np.y; pv2 += w[k] * np.z; pv3 += w[k] * np.w;
    }
    float sa0 = (1.0f - SMOOTH) * a.x + SMOOTH * av0;
    float sa1 = (1.0f - SMOOTH) * a.y + SMOOTH * av1;
    float sa2 = (1.0f - SMOOTH) * a.z + SMOOTH * av2;
    float sa3 = (1.0f - SMOOTH) * a.w + SMOOTH * av3;
    float sp0 = (1.0f - SMOOTH) * p.x + SMOOTH * pv0;
    float sp1 = (1.0f - SMOOTH) * p.y + SMOOTH * pv1;
    float sp2v = (1.0f - SMOOTH) * p.z + SMOOTH * pv2;
    float sp3 = (1.0f - SMOOTH) * p.w + SMOOTH * pv3;

    float cc = constant_offset[sid];
    float cm = linear_trend[sid];
    float cA0 = sa0 * __cosf(sp0),  cB0 = sa0 * __sinf(sp0);
    float cA1 = sa1 * __cosf(sp1),  cB1 = sa1 * __sinf(sp1);
    float cA2 = sa2 * __cosf(sp2v), cB2 = sa2 * __sinf(sp2v);
    float cA3 = sa3 * __cosf(sp3),  cB3 = sa3 * __sinf(sp3);

    // ---- Basis: 3 adjacent column pairs per thread, in registers ----
    const float w0 = TWO_PI / periods[0];
    const float w1 = TWO_PI / periods[1];
    const float w2 = TWO_PI / periods[2];
    const float w3 = TWO_PI / periods[3];

    f32x2 tv[NPAIR];
    f32x2 bs[NPAIR][4], bc[NPAIR][4];
    bool full[NPAIR], any[NPAIR];
    const int t0 = 2 * lane;

    #pragma unroll
    for (int q = 0; q < NPAIR; ++q) {
        const int t = t0 + 128 * q;
        const bool v0 = (t < T), v1 = (t + 1 < T);
        any[q] = v0; full[q] = v1;
        float ta = v0 ? time_vector[t]     : 0.f;
        float tb = v1 ? time_vector[t + 1] : 0.f;
        f32x2 tvp; tvp.x = ta; tvp.y = tb;
        tv[q] = tvp;
        #pragma unroll
        for (int f = 0; f < 4; ++f) {
            const float wf = (f == 0) ? w0 : (f == 1) ? w1 : (f == 2) ? w2 : w3;
            f32x2 s, c;
            s.x = __sinf(wf * ta); s.y = __sinf(wf * tb);
            c.x = __cosf(wf * ta); c.y = __cosf(wf * tb);
            bs[q][f] = s; bc[q][f] = c;
        }
    }

    float* wlds = lds + (size_t)wave * HROWS * T;   // wave-private slab

    if (send == SPW) {
        // ---- Fast path: two half-slabs of HROWS rows each ----
        #pragma unroll
        for (int half = 0; half < 2; ++half) {
            #pragma unroll
            for (int j4 = 0; j4 < HROWS; ++j4) {
                const int j = half * HROWS + j4;
                float sc  = rlane(cc,  j), sm  = rlane(cm,  j);
                float sA0 = rlane(cA0, j), sB0 = rlane(cB0, j);
                float sA1 = rlane(cA1, j), sB1 = rlane(cB1, j);
                float sA2 = rlane(cA2, j), sB2 = rlane(cB2, j);
                float sA3 = rlane(cA3, j), sB3 = rlane(cB3, j);
                float* lrow = wlds + j4 * T;

                #pragma unroll
                for (int q = 0; q < NPAIR; ++q) {
                    f32x2 sig = sp2(sc) + sp2(sm) * tv[q];
                    sig += sp2(sA0) * bs[q][0] + sp2(sB0) * bc[q][0];
                    sig += sp2(sA1) * bs[q][1] + sp2(sB1) * bc[q][1];
                    sig += sp2(sA2) * bs[q][2] + sp2(sB2) * bc[q][2];
                    sig += sp2(sA3) * bs[q][3] + sp2(sB3) * bc[q][3];
                    const int t = t0 + 128 * q;
                    // parity-safe paired b32 LDS writes (row base dword
                    // parity alternates with T odd)
                    if (full[q]) { lrow[t] = sig.x; lrow[t + 1] = sig.y; }
                    else if (any[q]) { lrow[t] = sig.x; }
                }
            }
            __builtin_amdgcn_sched_barrier(0);
            __builtin_amdgcn_wave_barrier();

            // ---- Cooperative aligned dwordx4 sweep of the half-slab ----
            // byte base = (wbase + half*HROWS)*T*4 : multiple of 16 since
            // (wbase + half*4) is a multiple of 4 and 4*T*4 = 16*T.
            const float4* src = reinterpret_cast<const float4*>(wlds);
            float4* dst = reinterpret_cast<float4*>(
                out + ((size_t)wbase + half * HROWS) * T);
            const int nch = T;                 // HROWS*T*4 / 16 = T chunks
            for (int it = lane; it < nch; it += 64)
                dst[it] = src[it];

            __builtin_amdgcn_sched_barrier(0);
            __builtin_amdgcn_wave_barrier();
        }
    } else {
        // ---- Tail path (N % SPW != 0): direct stores, correctness-first ----
        float* obase = out + (size_t)wbase * T;
        for (int j = 0; j < send; ++j) {
            float sc  = rlane(cc,  j), sm  = rlane(cm,  j);
            float sA0 = rlane(cA0, j), sB0 = rlane(cB0, j);
            float sA1 = rlane(cA1, j), sB1 = rlane(cB1, j);
            float sA2 = rlane(cA2, j), sB2 = rlane(cB2, j);
            float sA3 = rlane(cA3, j), sB3 = rlane(cB3, j);
            float* orow = obase + (size_t)j * T;
            #pragma unroll
            for (int q = 0; q < NPAIR; ++q) {
                f32x2 sig = sp2(sc) + sp2(sm) * tv[q];
                sig += sp2(sA0) * bs[q][0] + sp2(sB0) * bc[q][0];
                sig += sp2(sA1) * bs[q][1] + sp2(sB1) * bc[q][1];
                sig += sp2(sA2) * bs[q][2] + sp2(sB2) * bc[q][2];
                sig += sp2(sA3) * bs[q][3] + sp2(sB3) * bc[q][3];
                const int t = t0 + 128 * q;
                if (full[q]) { orow[t] = sig.x; orow[t + 1] = sig.y; }
                else if (any[q]) { orow[t] = sig.x; }
            }
        }
    }
}

extern "C" void kernel_launch(void* const* d_in, const int* in_sizes, int n_in,
                              void* d_out, int out_size, void* d_ws, size_t ws_size,
                              hipStream_t stream)
{
    const float* time_vector     = (const float*)d_in[0];
    const float* constant_offset = (const float*)d_in[1];
    const float* linear_trend    = (const float*)d_in[2];
    const float* amps            = (const float*)d_in[3];
    const float* phs             = (const float*)d_in[4];
    const float* wgt             = (const float*)d_in[5];
    const float* periods         = (const float*)d_in[6];
    const int*   nbidx           = (const int*)d_in[7];

    int T = in_sizes[0];
    int N = in_sizes[1];
    int K = in_sizes[5] / N;
    float* out = (float*)d_out;

    int grid = (N + SPB - 1) / SPB;
    size_t shmem = (size_t)WAVES * HROWS * T * sizeof(float);   // 23360 B @ T=365
    fused_v7<<<grid, BLOCK, shmem, stream>>>(
        time_vector, constant_offset, linear_trend, amps, phs, wgt,
        periods, nbidx, out, N, T, K);
}